// Round 11
// baseline (725.096 us; speedup 1.0000x reference)
//
#include <hip/hip_runtime.h>

// SSIM over (32,3,512,512) fp32 pairs, 11x11 gaussian sigma=1.5, VALID conv,
// scalar mean output.
//
// R8: barrier-free wave-autonomous rewrite. Evidence: VALUBusy invariant at
// 45-49% across occupancy 3/4/6 blk/CU, LDS size, conflicts, redundancy
// (R4-R7) => resident waves stall in lockstep (barrier-induced convoy), and
// ~80 of ~179 VALU instr/px are LDS-handoff overhead. New structure: each
// WAVE owns (image, 12-row chunk, full 512-col row); lane owns cols
// 8l..8l+7 (64x8=512 exact). Vertical 11-tap conv streams 12 rows per 2
// output rows into packed accumulators (4ch x 2row x 4vf2 = 64 VGPR);
// horizontal conv gets its 10-col halo via __shfl_down from lanes l+1,l+2.
// NO __syncthreads in the loop, NO LDS staging, no window-shift movs.
// 6x row-load redundancy is L2/L3-served (per-wave working set 24 KB;
// inputs L3-resident). Lanes 62/63 shuffle-wrap garbage only reaches
// cols >= 502 (discarded by the col guard).

namespace {
constexpr int IMG_H = 512;
constexpr int IMG_W = 512;
constexpr int NIMG  = 96;                       // B*C = 32*3
constexpr int OUT_H = 502;
constexpr int OUT_W = 502;
constexpr int RPW   = 12;                       // output rows per wave chunk
constexpr int CHUNKS = (OUT_H + RPW - 1) / RPW; // 42
constexpr int NWAVES = NIMG * CHUNKS;           // 4032 waves = 1008 blocks
constexpr int HW    = IMG_H * IMG_W;
constexpr double TOTAL = 24192384.0;            // 96*502*502

// exp(-k^2/4.5) for k=5..1, normalized at compile time
constexpr double U0 = 0.0038659201;
constexpr double U1 = 0.0285655007;
constexpr double U2 = 0.1353352832366127;
constexpr double U3 = 0.4111122898;
constexpr double U4 = 0.8007374026;
constexpr double S  = 1.0 + 2.0 * (U0 + U1 + U2 + U3 + U4);
}

typedef float vf2 __attribute__((ext_vector_type(2)));
typedef float vf4 __attribute__((ext_vector_type(4)));

__device__ __forceinline__ vf2 pk_fma(float w, vf2 a, vf2 c) {
    vf2 wv = {w, w};
    return __builtin_elementwise_fma(wv, a, c);   // -> v_pk_fma_f32
}

__global__ __launch_bounds__(256, 2) void ssim_main(const float* __restrict__ img1,
                                                    const float* __restrict__ img2,
                                                    double* __restrict__ acc)
{
    __shared__ float red[4];

    const float g[11] = {
        (float)(U0/S), (float)(U1/S), (float)(U2/S), (float)(U3/S), (float)(U4/S),
        (float)(1.0/S),
        (float)(U4/S), (float)(U3/S), (float)(U2/S), (float)(U1/S), (float)(U0/S)
    };
    constexpr float C1 = 1e-4f;   // 0.01^2
    constexpr float C2 = 9e-4f;   // 0.03^2

    const int t    = threadIdx.x;
    const int lane = t & 63;
    const int wv   = t >> 6;
    const int gw   = blockIdx.x * 4 + wv;          // 0 .. 4031
    const int z     = gw / CHUNKS;
    const int chunk = gw - z * CHUNKS;
    const int r0b   = chunk * RPW;
    const int row_end = min(r0b + RPW, OUT_H);

    const float* b1 = img1 + (size_t)z * HW + lane * 8;
    const float* b2 = img2 + (size_t)z * HW + lane * 8;

    float local = 0.f;

    for (int r0 = r0b; r0 < row_end; r0 += 2) {
        // ---- vertical 11-tap conv, streaming 12 rows, packed, 4 channels ----
        // max input row = 500 + 11 = 511 < IMG_H: in-bounds.
        vf2 a_[4][2][4];   // [ch][q][vf2-quad] : 64 VGPR
        #pragma unroll
        for (int ch = 0; ch < 4; ++ch)
            #pragma unroll
            for (int q = 0; q < 2; ++q)
                #pragma unroll
                for (int i = 0; i < 4; ++i) a_[ch][q][i] = (vf2){0.f, 0.f};

        #pragma unroll
        for (int j = 0; j < 12; ++j) {
            const float* r1 = b1 + (r0 + j) * IMG_W;
            const float* r2 = b2 + (r0 + j) * IMG_W;
            const vf4 xlo = *(const vf4*)r1;
            const vf4 xhi = *(const vf4*)(r1 + 4);
            const vf4 ylo = *(const vf4*)r2;
            const vf4 yhi = *(const vf4*)(r2 + 4);
            vf2 xs[4] = {xlo.xy, xlo.zw, xhi.xy, xhi.zw};
            vf2 ys[4] = {ylo.xy, ylo.zw, yhi.xy, yhi.zw};
            vf2 pp[4], xy[4];
            #pragma unroll
            for (int i = 0; i < 4; ++i) {
                pp[i] = __builtin_elementwise_fma(ys[i], ys[i], xs[i] * xs[i]);
                xy[i] = xs[i] * ys[i];
            }
            #pragma unroll
            for (int q = 0; q < 2; ++q) {
                const int k = j - q;
                if (k >= 0 && k < 11) {
                    const float w = g[k];
                    #pragma unroll
                    for (int i = 0; i < 4; ++i) {
                        a_[0][q][i] = pk_fma(w, xs[i], a_[0][q][i]);
                        a_[1][q][i] = pk_fma(w, ys[i], a_[1][q][i]);
                        a_[2][q][i] = pk_fma(w, pp[i], a_[2][q][i]);
                        a_[3][q][i] = pk_fma(w, xy[i], a_[3][q][i]);
                    }
                }
            }
        }

        // ---- horizontal 11-tap conv via lane shuffles + SSIM, per output row ----
        #pragma unroll
        for (int q = 0; q < 2; ++q) {
            if (r0 + q < row_end) {
                float hh[4][8];
                #pragma unroll
                for (int ch = 0; ch < 4; ++ch) {
                    const vf2 a0 = a_[ch][q][0], a1 = a_[ch][q][1];
                    const vf2 a2 = a_[ch][q][2], a3 = a_[ch][q][3];
                    // halo: 8 cols from lane+1, 2 cols from lane+2
                    float f[18];
                    f[0]  = a0.x; f[1]  = a0.y; f[2]  = a1.x; f[3]  = a1.y;
                    f[4]  = a2.x; f[5]  = a2.y; f[6]  = a3.x; f[7]  = a3.y;
                    f[8]  = __shfl_down(a0.x, 1, 64);
                    f[9]  = __shfl_down(a0.y, 1, 64);
                    f[10] = __shfl_down(a1.x, 1, 64);
                    f[11] = __shfl_down(a1.y, 1, 64);
                    f[12] = __shfl_down(a2.x, 1, 64);
                    f[13] = __shfl_down(a2.y, 1, 64);
                    f[14] = __shfl_down(a3.x, 1, 64);
                    f[15] = __shfl_down(a3.y, 1, 64);
                    f[16] = __shfl_down(a0.x, 2, 64);
                    f[17] = __shfl_down(a0.y, 2, 64);
                    #pragma unroll
                    for (int o = 0; o < 8; ++o) {
                        float s = 0.f;
                        #pragma unroll
                        for (int k = 0; k < 11; ++k) s = fmaf(g[k], f[o + k], s);
                        hh[ch][o] = s;
                    }
                }
                #pragma unroll
                for (int o = 0; o < 8; ++o) {
                    const int col = lane * 8 + o;
                    if (col < OUT_W) {
                        const float mu1 = hh[0][o], mu2 = hh[1][o];
                        const float ee  = hh[2][o], e12 = hh[3][o];
                        const float mu11 = mu1 * mu1;
                        const float mu22 = mu2 * mu2;
                        const float mu12 = mu1 * mu2;
                        const float mm   = mu11 + mu22;
                        const float s12  = e12 - mu12;
                        const float spp  = ee - mm;          // s1 + s2
                        const float num = fmaf(2.f, mu12, C1) * fmaf(2.f, s12, C2);
                        const float den = (mm + C1) * (spp + C2);
                        local = fmaf(num, __builtin_amdgcn_rcpf(den), local);
                    }
                }
            }
        }
    }

    // ---------------- reduction: wave shuffle -> LDS -> double atomic ----------------
    #pragma unroll
    for (int off = 32; off > 0; off >>= 1) local += __shfl_down(local, off, 64);
    if (lane == 0) red[wv] = local;
    __syncthreads();   // only barrier in the kernel
    if (t == 0) {
        double s = (double)red[0] + (double)red[1] + (double)red[2] + (double)red[3];
        atomicAdd(acc, s);
    }
}

__global__ void ssim_fin(const double* __restrict__ acc, float* __restrict__ out)
{
    out[0] = (float)(acc[0] / TOTAL);
}

extern "C" void kernel_launch(void* const* d_in, const int* in_sizes, int n_in,
                              void* d_out, int out_size, void* d_ws, size_t ws_size,
                              hipStream_t stream)
{
    (void)in_sizes; (void)n_in; (void)out_size; (void)ws_size;
    const float* img1 = (const float*)d_in[0];
    const float* img2 = (const float*)d_in[1];
    double* acc = (double*)d_ws;

    hipMemsetAsync(d_ws, 0, sizeof(double), stream);
    hipLaunchKernelGGL(ssim_main, dim3(NWAVES / 4), dim3(256), 0, stream,
                       img1, img2, acc);
    hipLaunchKernelGGL(ssim_fin, dim3(1), dim3(1), 0, stream, acc, (float*)d_out);
}

// Round 13
// 240.067 us; speedup vs baseline: 3.0204x; 3.0204x over previous
//
#include <hip/hip_runtime.h>

// SSIM over (32,3,512,512) fp32 pairs, 11x11 gaussian sigma=1.5, VALID conv,
// scalar mean output. Fused separable conv, 4 v-stat channels (x, y, x2+y2,
// x*y) staged in LDS (XOR-swizzled), horizontal 11-tap conv + SSIM + mean.
//
// R9 (resubmit after broker timeout): R7 with RPB 48->24. Re-audit found
// residency was GRID-capped at ~4 blocks/CU in every clean round (960-1056
// blocks / 256 CU) — static LDS/VGPR headroom (8 blocks/CU at VGPR=60, LDS
// 17.9KB) was never usable. Grid 21x96 = 2016 = 7.9 blocks/CU doubles the
// latency-hiding wave pool; total VALU work unchanged (window redundancy
// 1.21->1.42 adds only L3-served loads). R8's wave-autonomous rewrite spilled
// (VGPR cap 128 vs ~150 demand, WRITE_SIZE 1GB) — reverted. Everything below
// except RPB identical to R7.

namespace {
constexpr int IMG_H = 512;
constexpr int IMG_W = 512;
constexpr int NIMG  = 96;            // B*C = 32*3
constexpr int OUT_H = 502;
constexpr int OUT_W = 502;
constexpr int RPB   = 24;            // output rows per block (21 x-blocks = 2016)
constexpr int QR    = 2;             // output rows per inner iteration
constexpr int WIN   = QR + 10;       // rolling window rows (12)
constexpr int BUFW  = 544;           // 136 col4 slots * 4 floats (512 data + halo/pad)
constexpr double TOTAL = 24192384.0; // 96*502*502

// exp(-k^2/4.5) for k=5..1, normalized at compile time
constexpr double U0 = 0.0038659201;
constexpr double U1 = 0.0285655007;
constexpr double U2 = 0.1353352832366127;
constexpr double U3 = 0.4111122898;
constexpr double U4 = 0.8007374026;
constexpr double S  = 1.0 + 2.0 * (U0 + U1 + U2 + U3 + U4);
}

typedef float vf2 __attribute__((ext_vector_type(2)));

__device__ __forceinline__ vf2 pk_fma(float w, vf2 a, vf2 c) {
    vf2 wv = {w, w};
    return __builtin_elementwise_fma(wv, a, c);   // -> v_pk_fma_f32
}

__global__ __launch_bounds__(256, 3) void ssim_main(const float* __restrict__ img1,
                                                    const float* __restrict__ img2,
                                                    double* __restrict__ acc)
{
    __shared__ __align__(16) float vrow[QR][4][BUFW];   // 17408 B
    __shared__ float red[4];

    const float g[11] = {
        (float)(U0/S), (float)(U1/S), (float)(U2/S), (float)(U3/S), (float)(U4/S),
        (float)(1.0/S),
        (float)(U4/S), (float)(U3/S), (float)(U2/S), (float)(U1/S), (float)(U0/S)
    };
    constexpr float C1 = 1e-4f;   // 0.01^2
    constexpr float C2 = 9e-4f;   // 0.03^2

    const int t   = threadIdx.x;
    const int z   = blockIdx.y;
    const int oy0 = blockIdx.x * RPB;
    const int row_end = min(oy0 + RPB, OUT_H);

    const vf2* p1 = (const vf2*)(img1 + (size_t)z * (IMG_H * IMG_W)) + t;
    const vf2* p2 = (const vf2*)(img2 + (size_t)z * (IMG_H * IMG_W)) + t;

    // phase-V: thread owns input cols 2t, 2t+1. Swizzled write offset.
    const int c4w  = t >> 1;
    const int woff = ((c4w ^ ((c4w >> 3) & 7)) << 2) + ((t & 1) << 1);

    // phase-H: thread = (row hq 0..1, 4-col group at cb). Swizzled read offsets.
    const int hq = t >> 7;            // 0..1, all 256 threads active
    const int cb = (t & 127) << 2;    // 0..508
    int roff[4];
    #pragma unroll
    for (int k = 0; k < 4; ++k) {
        int c4 = (cb >> 2) + k;       // <= 130 < 136 slots
        roff[k] = (c4 ^ ((c4 >> 3) & 7)) << 2;
    }

    // rolling window: rows r0 .. r0+9 live at loop top
    vf2 wx[WIN], wy[WIN];
    #pragma unroll
    for (int j = 0; j < WIN - QR; ++j) {
        wx[j] = p1[(oy0 + j) * (IMG_W / 2)];
        wy[j] = p2[(oy0 + j) * (IMG_W / 2)];
    }

    float local = 0.f;

    for (int r0 = oy0; r0 < row_end; r0 += QR) {
        // ---- load the 2 new window rows (issued early, overlap with conv) ----
        #pragma unroll
        for (int i = 0; i < QR; ++i) {
            const int row = min(r0 + (WIN - QR) + i, IMG_H - 1);  // clamp: tail only
            wx[WIN - QR + i] = p1[row * (IMG_W / 2)];
            wy[WIN - QR + i] = p2[row * (IMG_W / 2)];
        }

        // ---- phase V: vertical 11-tap conv over the window, 4 channels, packed ----
        vf2 am1[QR], am2[QR], app[QR], axy[QR];
        #pragma unroll
        for (int q = 0; q < QR; ++q) {
            am1[q] = (vf2){0.f, 0.f};
            am2[q] = (vf2){0.f, 0.f};
            app[q] = (vf2){0.f, 0.f};
            axy[q] = (vf2){0.f, 0.f};
        }
        #pragma unroll
        for (int j = 0; j < WIN; ++j) {
            const vf2 x = wx[j], y = wy[j];
            const vf2 pp = __builtin_elementwise_fma(y, y, x * x);  // x^2 + y^2
            const vf2 xy = x * y;
            #pragma unroll
            for (int q = 0; q < QR; ++q) {
                const int k = j - q;
                if (k >= 0 && k < 11) {
                    const float w = g[k];
                    am1[q] = pk_fma(w, x,  am1[q]);
                    am2[q] = pk_fma(w, y,  am2[q]);
                    app[q] = pk_fma(w, pp, app[q]);
                    axy[q] = pk_fma(w, xy, axy[q]);
                }
            }
        }
        __syncthreads();   // previous iteration's phase-H reads complete
        #pragma unroll
        for (int q = 0; q < QR; ++q) {
            *(vf2*)&vrow[q][0][woff] = am1[q];
            *(vf2*)&vrow[q][1][woff] = am2[q];
            *(vf2*)&vrow[q][2][woff] = app[q];
            *(vf2*)&vrow[q][3][woff] = axy[q];
        }
        __syncthreads();   // v-stats visible

        // ---- shift window now: old rows die before phase-H's register peak ----
        #pragma unroll
        for (int j = 0; j < WIN - QR; ++j) { wx[j] = wx[j + QR]; wy[j] = wy[j + QR]; }

        // ---- phase H: horizontal 11-tap conv + SSIM, 4 cols/thread ----
        const int rr = r0 + hq;
        if (rr < row_end && cb < OUT_W) {
            float aa[4][4];
            #pragma unroll
            for (int ch = 0; ch < 4; ++ch) {
                const float* bc = &vrow[hq][ch][0];
                float f[16];
                #pragma unroll
                for (int k = 0; k < 4; ++k) {
                    float4 v = *(const float4*)(bc + roff[k]);
                    f[4*k+0] = v.x; f[4*k+1] = v.y; f[4*k+2] = v.z; f[4*k+3] = v.w;
                }
                #pragma unroll
                for (int j = 0; j < 4; ++j) {
                    float s = 0.f;
                    #pragma unroll
                    for (int k = 0; k < 11; ++k) s = fmaf(g[k], f[j + k], s);
                    aa[ch][j] = s;
                }
            }
            #pragma unroll
            for (int j = 0; j < 4; ++j) {
                if (cb + j < OUT_W) {
                    float mu1 = aa[0][j], mu2 = aa[1][j];
                    float ee  = aa[2][j], e12 = aa[3][j];
                    float mu11 = mu1 * mu1;
                    float mu22 = mu2 * mu2;
                    float mu12 = mu1 * mu2;
                    float mm   = mu11 + mu22;
                    float s12  = e12 - mu12;
                    float spp  = ee - mm;            // s1 + s2
                    float num = fmaf(2.f, mu12, C1) * fmaf(2.f, s12, C2);
                    float den = (mm + C1) * (spp + C2);
                    local = fmaf(num, __builtin_amdgcn_rcpf(den), local);
                }
            }
        }
    }

    // ---------------- reduction: wave shuffle -> LDS -> double atomic ----------------
    #pragma unroll
    for (int off = 32; off > 0; off >>= 1) local += __shfl_down(local, off, 64);
    if ((t & 63) == 0) red[t >> 6] = local;
    __syncthreads();
    if (t == 0) {
        double s = (double)red[0] + (double)red[1] + (double)red[2] + (double)red[3];
        atomicAdd(acc, s);
    }
}

__global__ void ssim_fin(const double* __restrict__ acc, float* __restrict__ out)
{
    out[0] = (float)(acc[0] / TOTAL);
}

extern "C" void kernel_launch(void* const* d_in, const int* in_sizes, int n_in,
                              void* d_out, int out_size, void* d_ws, size_t ws_size,
                              hipStream_t stream)
{
    (void)in_sizes; (void)n_in; (void)out_size; (void)ws_size;
    const float* img1 = (const float*)d_in[0];
    const float* img2 = (const float*)d_in[1];
    double* acc = (double*)d_ws;

    hipMemsetAsync(d_ws, 0, sizeof(double), stream);
    dim3 grid((OUT_H + RPB - 1) / RPB, NIMG);   // 21 x 96 = 2016 blocks
    hipLaunchKernelGGL(ssim_main, grid, dim3(256), 0, stream, img1, img2, acc);
    hipLaunchKernelGGL(ssim_fin, dim3(1), dim3(1), 0, stream, acc, (float*)d_out);
}